// Round 1
// baseline (313.107 us; speedup 1.0000x reference)
//
#include <hip/hip_runtime.h>

#define D    128
#define BROW 32     // ints per bucket entry row (entries 0..30 used; word 31 pad)
#define CAPE 31     // entries per bucket; P(deg>=31) ~ 1e-13 per slot

typedef short short8 __attribute__((ext_vector_type(8)));
typedef float f32x4  __attribute__((ext_vector_type(4)));

static __device__ __forceinline__ unsigned short f2bf(float f) {
    union { float f; unsigned u; } v; v.f = f;
    unsigned r = v.u + 0x7FFFu + ((v.u >> 16) & 1u);   // RNE
    return (unsigned short)(r >> 16);
}
static __device__ __forceinline__ float bf2f(unsigned short h) {
    union { unsigned u; float f; } v; v.u = ((unsigned)h) << 16;
    return v.f;
}

// ---------------------------------------------------------------------------
// Phase-0 mega-kernel (grid-partitioned):
//  blocks [0, nbuild)        : bucket build. cnt[2N] (compact, hot) counts via
//                              atomicAdd; entries go to ent[g*32 + p].
//                              All atomics issued before any dependent store
//                              (two-loop split) -> 4-deep atomic MLP/thread.
//  blocks [nbuild, +ncvt)    : x fp32 -> xb bf16
//  blocks [nbuild+ncvt, +24) : weights -> bf16, scaled, MFMA-B-fragment order
// Bucket space g in [0,2N): g<N = st (in-nbrs of dst g); g>=N = ts (out-nbrs
// of src g-N).
// ---------------------------------------------------------------------------
__global__ __launch_bounds__(256) void k_phase0(
    const float* __restrict__ x, const int* __restrict__ ei,
    const float* __restrict__ W_lin, const float* __restrict__ W_st,
    const float* __restrict__ W_ts,
    unsigned short* __restrict__ xb, unsigned short* __restrict__ wtf,
    int* __restrict__ cnt, int* __restrict__ ent,
    int E, int N, int t8, int nbuild, int ncvt)
{
    int b = blockIdx.x;
    if (b < nbuild) {
        int e0 = b * 512 + threadIdx.x;       // 2 edges per thread
        int s[2], d[2], p[2], q[2];
        #pragma unroll
        for (int k = 0; k < 2; ++k) {
            int e = e0 + k * 256;
            if (e < E) { s[k] = ei[e]; d[k] = ei[E + e]; } else { s[k] = -1; }
        }
        // loop 1: issue all atomics (no result consumed -> no waits between)
        #pragma unroll
        for (int k = 0; k < 2; ++k)
            if (s[k] >= 0) {
                p[k] = atomicAdd(cnt + d[k], 1);
                q[k] = atomicAdd(cnt + N + s[k], 1);
            }
        // loop 2: dependent entry stores (results arrive pipelined)
        #pragma unroll
        for (int k = 0; k < 2; ++k)
            if (s[k] >= 0) {
                if (p[k] < CAPE) ent[(size_t)d[k] * BROW + p[k]] = s[k];
                if (q[k] < CAPE) ent[(size_t)(N + s[k]) * BROW + q[k]] = d[k];
            }
    } else if (b < nbuild + ncvt) {
        int i = (b - nbuild) * 256 + threadIdx.x;   // 8 floats per thread
        if (i >= t8) return;
        const float4* p = (const float4*)(x + (size_t)i * 8);
        float4 a = p[0], c = p[1];
        unsigned r0 = (unsigned)f2bf(a.x) | ((unsigned)f2bf(a.y) << 16);
        unsigned r1 = (unsigned)f2bf(a.z) | ((unsigned)f2bf(a.w) << 16);
        unsigned r2 = (unsigned)f2bf(c.x) | ((unsigned)f2bf(c.y) << 16);
        unsigned r3 = (unsigned)f2bf(c.z) | ((unsigned)f2bf(c.w) << 16);
        *((uint4*)(xb + (size_t)i * 8)) = make_uint4(r0, r1, r2, r3);
    } else {
        // wtf[((m*4+ks)*8+tile)*64+lane][j] =
        //   scale_m * W_m[ks*32+(lane>>4)*8+j][tile*16+(lane&15)]
        int g = (b - nbuild - ncvt) * 256 + threadIdx.x;
        if (g >= 3 * 4 * 8 * 64) return;
        int lane = g & 63;
        int tile = (g >> 6) & 7;
        int ks   = (g >> 9) & 3;
        int m    = g >> 11;
        const float* W = (m == 0) ? W_lin : (m == 1) ? W_st : W_ts;
        float scale = (m == 0) ? 1.0f : 0.5f;
        int n = tile * 16 + (lane & 15);
        int kbase = ks * 32 + (lane >> 4) * 8;
        unsigned short* dst = wtf + (size_t)g * 8;
        #pragma unroll
        for (int j = 0; j < 8; ++j)
            dst[j] = f2bf(W[(size_t)(kbase + j) * D + n] * scale);
    }
}

// ---------------------------------------------------------------------------
// Fused gather-mean + K=384 bf16 MFMA GEMM. Block = 256 thr = 4 waves,
// 64 output rows. LDS = 32 KB only -> 5 blocks/CU.
// Phase A: 16 groups x 16 lanes; each group owns 8 consecutive slots
//   (slot = grp*8+s; dir = slot>>6, i = slot&63). Lane l16 reads ushort8 at
//   k = l16*8 (16 B/lane, full 256-B row per group-load). Software pipeline:
//   bucket-row int4 + cnt for slot s+1 issued before gathering slot s, so the
//   entry-line miss hides under the previous slot's gathers. Entry words j>=4
//   re-read from the (now L1/L2-hot) line.
//   Lane l16 owns k = l16*8..+7 == unit (ks=l16>>2, qd=l16&3) of the A-frag
//   layout -> one ds_write_b128 per slot, layout identical to before.
// Phase B: out = [xb | agg_st | agg_ts] @ [Wl; .5Wst; .5Wts] + bias (MFMA).
// ---------------------------------------------------------------------------
__global__ __launch_bounds__(256, 5) void k_fused(
    const unsigned short* __restrict__ xb,
    const int* __restrict__ cnt, const int* __restrict__ ent,
    const unsigned short* __restrict__ wtf,
    const float* __restrict__ b_lin, const float* __restrict__ b_st,
    const float* __restrict__ b_ts,
    float* __restrict__ out, int N)
{
    __shared__ unsigned short aggF[2 * 4 * 64 * 4 * 8];   // 16384 ushorts = 32 KB

    const int tid  = threadIdx.x;
    const int row0 = blockIdx.x * 64;

    // ---- Phase A: gather means into A-fragment-ordered LDS ----
    {
        const int grp = tid >> 4;        // 16 groups of 16 lanes
        const int l16 = tid & 15;
        const int ks  = l16 >> 2;
        const int qd  = l16 & 3;
        const unsigned short* xrow = xb + (l16 << 3);   // lane's 16-B column

        // prologue: prefetch slot 0's entry line + count
        int slot = grp * 8;
        int dir0 = slot >> 6, ii = slot & 63;
        int gn = row0 + ii; if (gn > N - 1) gn = N - 1;
        size_t g = (size_t)dir0 * N + gn;
        const int* row = ent + g * BROW;
        int4 h = *(const int4*)row;      // entries 0..3 (+ warms the line)
        int dg = cnt[g];

        for (int s = 0; s < 8; ++s) {
            // issue next slot's prefetch before consuming current
            const int* rowN = row; int4 hn = h; int dgn = dg;
            if (s < 7) {
                int slot1 = grp * 8 + s + 1;
                int dir1 = slot1 >> 6, i1 = slot1 & 63;
                int gn1 = row0 + i1; if (gn1 > N - 1) gn1 = N - 1;
                size_t g1 = (size_t)dir1 * N + gn1;
                rowN = ent + g1 * BROW;
                hn = *(const int4*)rowN;
                dgn = cnt[g1];
            }
            int slotc = grp * 8 + s;
            int dirc = slotc >> 6, ic = slotc & 63;
            int deg = dg > CAPE ? CAPE : dg;

            float a[8];
            #pragma unroll
            for (int t = 0; t < 8; ++t) a[t] = 0.f;

            int j = 0;
            if (deg >= 4) {
                {   // first 4 neighbors from prefetched h (no extra round-trip)
                    short8 u0 = *(const short8*)(xrow + (size_t)h.x * D);
                    short8 u1 = *(const short8*)(xrow + (size_t)h.y * D);
                    short8 u2 = *(const short8*)(xrow + (size_t)h.z * D);
                    short8 u3 = *(const short8*)(xrow + (size_t)h.w * D);
                    #pragma unroll
                    for (int t = 0; t < 8; ++t)
                        a[t] += (bf2f((unsigned short)u0[t]) + bf2f((unsigned short)u1[t]))
                              + (bf2f((unsigned short)u2[t]) + bf2f((unsigned short)u3[t]));
                }
                for (j = 4; j + 4 <= deg; j += 4) {
                    int n0 = row[j], n1 = row[j + 1], n2 = row[j + 2], n3 = row[j + 3];
                    short8 u0 = *(const short8*)(xrow + (size_t)n0 * D);
                    short8 u1 = *(const short8*)(xrow + (size_t)n1 * D);
                    short8 u2 = *(const short8*)(xrow + (size_t)n2 * D);
                    short8 u3 = *(const short8*)(xrow + (size_t)n3 * D);
                    #pragma unroll
                    for (int t = 0; t < 8; ++t)
                        a[t] += (bf2f((unsigned short)u0[t]) + bf2f((unsigned short)u1[t]))
                              + (bf2f((unsigned short)u2[t]) + bf2f((unsigned short)u3[t]));
                }
            }
            for (; j < deg; ++j) {        // tail (line is L1-hot)
                int n = row[j];
                short8 u = *(const short8*)(xrow + (size_t)n * D);
                #pragma unroll
                for (int t = 0; t < 8; ++t) a[t] += bf2f((unsigned short)u[t]);
            }

            float inv = 1.0f / fmaxf((float)deg, 1.0f);
            short8 o;
            #pragma unroll
            for (int t = 0; t < 8; ++t) o[t] = (short)f2bf(a[t] * inv);
            // unit index: ((dir*4+ks)*64 + i)*4 + qd
            ((short8*)aggF)[(((dirc * 4 + ks) * 64 + ic) * 4) + qd] = o;

            row = rowN; h = hn; dg = dgn;
        }
    }
    __syncthreads();

    // ---- Phase B: MFMA GEMM ----
    const int w    = tid >> 6;
    const int lane = tid & 63;
    const int quad = lane >> 4;
    const int l15  = lane & 15;
    const int wrow = w * 16 + l15;     // local row 0..63
    int rowA = row0 + wrow; if (rowA > N - 1) rowA = N - 1;

    f32x4 acc[8];
    #pragma unroll
    for (int t = 0; t < 8; ++t) acc[t] = (f32x4){0.f, 0.f, 0.f, 0.f};

    for (int m = 0; m < 3; ++m) {
        short8 a[4];
        if (m == 0) {
            const unsigned short* ap = xb + (size_t)rowA * D + quad * 8;
            #pragma unroll
            for (int ks = 0; ks < 4; ++ks)
                a[ks] = *(const short8*)(ap + ks * 32);
        } else {
            const short8* af = (const short8*)aggF;
            #pragma unroll
            for (int ks = 0; ks < 4; ++ks)
                a[ks] = af[(((m - 1) * 4 + ks) << 8) + wrow * 4 + quad];
        }
        const short8* bw = ((const short8*)wtf) + m * 2048;   // 4*8*64 units per m
        #pragma unroll
        for (int ks = 0; ks < 4; ++ks) {
            #pragma unroll
            for (int t = 0; t < 8; ++t) {
                short8 bb = bw[(ks * 8 + t) * 64 + lane];
                acc[t] = __builtin_amdgcn_mfma_f32_16x16x32_bf16(a[ks], bb, acc[t], 0, 0, 0);
            }
        }
    }

    // epilogue: C/D map col=lane&15, row(local) = w*16 + quad*4 + reg
    // nontemporal: out is write-only, keep L2 for gather-hot xb/ent
    #pragma unroll
    for (int t = 0; t < 8; ++t) {
        int col = t * 16 + l15;
        float bj = b_lin[col] + 0.5f * (b_st[col] + b_ts[col]);
        #pragma unroll
        for (int i = 0; i < 4; ++i) {
            int row = row0 + w * 16 + quad * 4 + i;
            if (row < N)
                __builtin_nontemporal_store(acc[t][i] + bj, &out[(size_t)row * D + col]);
        }
    }
}

extern "C" void kernel_launch(void* const* d_in, const int* in_sizes, int n_in,
                              void* d_out, int out_size, void* d_ws, size_t ws_size,
                              hipStream_t stream)
{
    const float* x     = (const float*)d_in[0];
    const int*   ei    = (const int*)d_in[1];
    const float* W_lin = (const float*)d_in[2];
    const float* b_lin = (const float*)d_in[3];
    const float* W_st  = (const float*)d_in[4];
    const float* b_st  = (const float*)d_in[5];
    const float* W_ts  = (const float*)d_in[6];
    const float* b_ts  = (const float*)d_in[7];
    float*       out   = (float*)d_out;

    const int N = in_sizes[0] / D;
    const int E = in_sizes[1] / 2;
    const int M = 2 * N;

    char* base = (char*)d_ws;
    int* cnt             = (int*)base;            base += (size_t)M * 4;         // 0.8 MB
    int* ent             = (int*)base;            base += (size_t)M * BROW * 4;  // 25.6 MB
    unsigned short* xb   = (unsigned short*)base; base += (size_t)N * D * 2;     // 25.6 MB
    unsigned short* wtf  = (unsigned short*)base; base += 3 * 16384 * 2;         // 0.1 MB

    // only the compact count array needs zeroing (entries written before read)
    hipMemsetAsync(cnt, 0, (size_t)M * 4, stream);

    const int t8     = N * D / 8;
    const int nbuild = (E + 511) / 512;
    const int ncvt   = (t8 + 255) / 256;
    const int nprep  = 24;

    k_phase0<<<dim3(nbuild + ncvt + nprep), dim3(256), 0, stream>>>(
        x, ei, W_lin, W_st, W_ts, xb, wtf, cnt, ent, E, N, t8, nbuild, ncvt);
    k_fused<<<dim3((N + 63) / 64), dim3(256), 0, stream>>>(
        xb, cnt, ent, wtf, b_lin, b_st, b_ts, out, N);
}

// Round 2
// 269.368 us; speedup vs baseline: 1.1624x; 1.1624x over previous
//
#include <hip/hip_runtime.h>

#define D    128
#define BROW 32     // ints per bucket entry row (entries 0..30 used; word 31 pad)
#define CAPE 31     // entries per bucket; P(deg>=31) ~ 1e-13 per slot

typedef short short8 __attribute__((ext_vector_type(8)));
typedef float f32x4  __attribute__((ext_vector_type(4)));

static __device__ __forceinline__ unsigned short f2bf(float f) {
    union { float f; unsigned u; } v; v.f = f;
    unsigned r = v.u + 0x7FFFu + ((v.u >> 16) & 1u);   // RNE
    return (unsigned short)(r >> 16);
}
static __device__ __forceinline__ float bf2f(unsigned short h) {
    union { unsigned u; float f; } v; v.u = ((unsigned)h) << 16;
    return v.f;
}

// ---------------------------------------------------------------------------
// Phase-0 mega-kernel (grid-partitioned):
//  blocks [0, nbuild)        : XCD-partitioned bucket build.
//      nbuild = 8 * nchunk; block b = (chunk = b>>3, part = b&7).
//      Partition p owns bucket range [p*P, (p+1)*P), P = ceil(2N/8) -> its
//      3.2 MB slice of ent fits one XCD's 4 MiB L2. With round-robin
//      blockIdx->XCD dispatch the entry stores are L2-local and evict as
//      full lines (perf heuristic only — correct under any mapping).
//      Counts via device-scope atomicAdd on compact cnt[2N] (memory-side);
//      all atomics issued before any dependent store (MLP).
//  blocks [nbuild, +ncvt)    : x fp32 -> xb bf16
//  blocks [nbuild+ncvt, +24) : weights -> bf16, scaled, MFMA-B-fragment order
// Bucket space g in [0,2N): g<N = st (in-nbrs of dst g); g>=N = ts (out-nbrs
// of src g-N).
// ---------------------------------------------------------------------------
#define CH 2048     // edges per chunk (8 per thread)

__global__ __launch_bounds__(256) void k_phase0(
    const float* __restrict__ x, const int* __restrict__ ei,
    const float* __restrict__ W_lin, const float* __restrict__ W_st,
    const float* __restrict__ W_ts,
    unsigned short* __restrict__ xb, unsigned short* __restrict__ wtf,
    int* __restrict__ cnt, int* __restrict__ ent,
    int E, int N, int t8, int nbuild, int ncvt)
{
    int b = blockIdx.x;
    if (b < nbuild) {
        const int part  = b & 7;
        const int chunk = b >> 3;
        const int P  = (2 * N + 7) >> 3;
        const int lo = part * P;
        const int hi = lo + P;
        int gg[16], vv[16], pp[16];
        #pragma unroll
        for (int k = 0; k < 8; ++k) {
            int e = chunk * CH + k * 256 + threadIdx.x;
            int s = -1, d = -1;
            if (e < E) { s = ei[e]; d = ei[E + e]; }
            int gts = N + s;
            gg[2 * k]     = (s >= 0 && d >= lo && d < hi) ? d : -1;
            vv[2 * k]     = s;
            gg[2 * k + 1] = (s >= 0 && gts >= lo && gts < hi) ? gts : -1;
            vv[2 * k + 1] = d;
        }
        // loop 1: issue all atomics (no result consumed between -> deep MLP)
        #pragma unroll
        for (int k = 0; k < 16; ++k)
            if (gg[k] >= 0) pp[k] = atomicAdd(cnt + gg[k], 1);
        // loop 2: dependent entry stores (L2-local under round-robin mapping)
        #pragma unroll
        for (int k = 0; k < 16; ++k)
            if (gg[k] >= 0 && pp[k] < CAPE)
                ent[(size_t)gg[k] * BROW + pp[k]] = vv[k];
    } else if (b < nbuild + ncvt) {
        int i = (b - nbuild) * 256 + threadIdx.x;   // 8 floats per thread
        if (i >= t8) return;
        const float4* p = (const float4*)(x + (size_t)i * 8);
        float4 a = p[0], c = p[1];
        unsigned r0 = (unsigned)f2bf(a.x) | ((unsigned)f2bf(a.y) << 16);
        unsigned r1 = (unsigned)f2bf(a.z) | ((unsigned)f2bf(a.w) << 16);
        unsigned r2 = (unsigned)f2bf(c.x) | ((unsigned)f2bf(c.y) << 16);
        unsigned r3 = (unsigned)f2bf(c.z) | ((unsigned)f2bf(c.w) << 16);
        *((uint4*)(xb + (size_t)i * 8)) = make_uint4(r0, r1, r2, r3);
    } else {
        // wtf[((m*4+ks)*8+tile)*64+lane][j] =
        //   scale_m * W_m[ks*32+(lane>>4)*8+j][tile*16+(lane&15)]
        int g = (b - nbuild - ncvt) * 256 + threadIdx.x;
        if (g >= 3 * 4 * 8 * 64) return;
        int lane = g & 63;
        int tile = (g >> 6) & 7;
        int ks   = (g >> 9) & 3;
        int m    = g >> 11;
        const float* W = (m == 0) ? W_lin : (m == 1) ? W_st : W_ts;
        float scale = (m == 0) ? 1.0f : 0.5f;
        int n = tile * 16 + (lane & 15);
        int kbase = ks * 32 + (lane >> 4) * 8;
        unsigned short* dst = wtf + (size_t)g * 8;
        #pragma unroll
        for (int j = 0; j < 8; ++j)
            dst[j] = f2bf(W[(size_t)(kbase + j) * D + n] * scale);
    }
}

// ---------------------------------------------------------------------------
// Fused gather-mean + K=384 bf16 MFMA GEMM. Block = 256 thr = 4 waves,
// 64 output rows. LDS = 32 KB only -> 5 blocks/CU.
// Phase A: 32 groups x 8 lanes; each group owns 4 consecutive slots
//   (slot = grp*4+s; dir = slot>>6, i = slot&63). Lane l8 reads 32 B
//   (2x short8) at k = l8*16 -> full 256-B row per group-load, 8 loads in
//   flight per lane per neighbor-quad. Software pipeline: next slot's
//   bucket-row int4 + cnt issued before gathering the current slot.
//   Lane l8 owns A-frag units 2*l8, 2*l8+1 (ks=l8>>1, qd=(l8&1)*2 +{0,1})
//   -> two ds_write_b128 per slot; layout identical to Phase B's reads.
// Phase B: out = [xb | agg_st | agg_ts] @ [Wl; .5Wst; .5Wts] + bias (MFMA).
//   m=0 (dense xb) pass runs BEFORE __syncthreads — no LDS dependency, its
//   MFMAs overlap other waves' Phase-A latency stalls.
// ---------------------------------------------------------------------------
__global__ __launch_bounds__(256, 5) void k_fused(
    const unsigned short* __restrict__ xb,
    const int* __restrict__ cnt, const int* __restrict__ ent,
    const unsigned short* __restrict__ wtf,
    const float* __restrict__ b_lin, const float* __restrict__ b_st,
    const float* __restrict__ b_ts,
    float* __restrict__ out, int N)
{
    __shared__ unsigned short aggF[2 * 4 * 64 * 4 * 8];   // 16384 ushorts = 32 KB

    const int tid  = threadIdx.x;
    const int row0 = blockIdx.x * 64;

    // ---- Phase A: gather means into A-fragment-ordered LDS ----
    {
        const int grp = tid >> 3;        // 32 groups of 8 lanes
        const int l8  = tid & 7;
        const int ks  = l8 >> 1;
        const int qd0 = (l8 & 1) * 2;
        const unsigned short* xcol = xb + (l8 << 4);   // lane's 32-B column

        // prologue: prefetch slot 0's entry line + count
        int slot0 = grp * 4;
        int gn = row0 + (slot0 & 63); if (gn > N - 1) gn = N - 1;
        size_t g = (size_t)(slot0 >> 6) * N + gn;
        const int* row = ent + g * BROW;
        int4 h = *(const int4*)row;      // entries 0..3 (+ warms the line)
        int dg = cnt[g];

        for (int s = 0; s < 4; ++s) {
            // issue next slot's prefetch before consuming current
            const int* rowN = row; int4 hn = h; int dgn = dg;
            if (s < 3) {
                int slot1 = grp * 4 + s + 1;
                int gn1 = row0 + (slot1 & 63); if (gn1 > N - 1) gn1 = N - 1;
                size_t g1 = (size_t)(slot1 >> 6) * N + gn1;
                rowN = ent + g1 * BROW;
                hn = *(const int4*)rowN;
                dgn = cnt[g1];
            }
            int slotc = grp * 4 + s;
            int dirc = slotc >> 6, ic = slotc & 63;
            int deg = dg > CAPE ? CAPE : dg;

            float a0[8], a1[8];
            #pragma unroll
            for (int t = 0; t < 8; ++t) { a0[t] = 0.f; a1[t] = 0.f; }

            int j = 0;
            if (deg >= 4) {
                {   // first 4 neighbors from prefetched h (no extra round-trip)
                    const unsigned short* r0 = xcol + (size_t)h.x * D;
                    const unsigned short* r1 = xcol + (size_t)h.y * D;
                    const unsigned short* r2 = xcol + (size_t)h.z * D;
                    const unsigned short* r3 = xcol + (size_t)h.w * D;
                    short8 u00 = *(const short8*)r0, u01 = *(const short8*)(r0 + 8);
                    short8 u10 = *(const short8*)r1, u11 = *(const short8*)(r1 + 8);
                    short8 u20 = *(const short8*)r2, u21 = *(const short8*)(r2 + 8);
                    short8 u30 = *(const short8*)r3, u31 = *(const short8*)(r3 + 8);
                    #pragma unroll
                    for (int t = 0; t < 8; ++t) {
                        a0[t] += (bf2f((unsigned short)u00[t]) + bf2f((unsigned short)u10[t]))
                               + (bf2f((unsigned short)u20[t]) + bf2f((unsigned short)u30[t]));
                        a1[t] += (bf2f((unsigned short)u01[t]) + bf2f((unsigned short)u11[t]))
                               + (bf2f((unsigned short)u21[t]) + bf2f((unsigned short)u31[t]));
                    }
                }
                for (j = 4; j + 4 <= deg; j += 4) {
                    const unsigned short* r0 = xcol + (size_t)row[j]     * D;
                    const unsigned short* r1 = xcol + (size_t)row[j + 1] * D;
                    const unsigned short* r2 = xcol + (size_t)row[j + 2] * D;
                    const unsigned short* r3 = xcol + (size_t)row[j + 3] * D;
                    short8 u00 = *(const short8*)r0, u01 = *(const short8*)(r0 + 8);
                    short8 u10 = *(const short8*)r1, u11 = *(const short8*)(r1 + 8);
                    short8 u20 = *(const short8*)r2, u21 = *(const short8*)(r2 + 8);
                    short8 u30 = *(const short8*)r3, u31 = *(const short8*)(r3 + 8);
                    #pragma unroll
                    for (int t = 0; t < 8; ++t) {
                        a0[t] += (bf2f((unsigned short)u00[t]) + bf2f((unsigned short)u10[t]))
                               + (bf2f((unsigned short)u20[t]) + bf2f((unsigned short)u30[t]));
                        a1[t] += (bf2f((unsigned short)u01[t]) + bf2f((unsigned short)u11[t]))
                               + (bf2f((unsigned short)u21[t]) + bf2f((unsigned short)u31[t]));
                    }
                }
            }
            for (; j < deg; ++j) {        // tail (line is L1-hot)
                const unsigned short* r = xcol + (size_t)row[j] * D;
                short8 u0 = *(const short8*)r, u1 = *(const short8*)(r + 8);
                #pragma unroll
                for (int t = 0; t < 8; ++t) {
                    a0[t] += bf2f((unsigned short)u0[t]);
                    a1[t] += bf2f((unsigned short)u1[t]);
                }
            }

            float inv = 1.0f / fmaxf((float)deg, 1.0f);
            short8 o0, o1;
            #pragma unroll
            for (int t = 0; t < 8; ++t) {
                o0[t] = (short)f2bf(a0[t] * inv);
                o1[t] = (short)f2bf(a1[t] * inv);
            }
            // unit index: ((dir*4+ks)*64 + i)*4 + qd
            short8* afp = ((short8*)aggF) + (((dirc * 4 + ks) * 64 + ic) * 4) + qd0;
            afp[0] = o0;
            afp[1] = o1;

            row = rowN; h = hn; dg = dgn;
        }
    }

    // ---- Phase B: MFMA GEMM ----
    const int w    = tid >> 6;
    const int lane = tid & 63;
    const int quad = lane >> 4;
    const int l15  = lane & 15;
    const int wrow = w * 16 + l15;     // local row 0..63
    int rowA = row0 + wrow; if (rowA > N - 1) rowA = N - 1;

    f32x4 acc[8];
    #pragma unroll
    for (int t = 0; t < 8; ++t) acc[t] = (f32x4){0.f, 0.f, 0.f, 0.f};

    // m = 0: dense xb pass, no LDS dependency -> before the barrier
    {
        short8 a[4];
        const unsigned short* ap = xb + (size_t)rowA * D + quad * 8;
        #pragma unroll
        for (int ks = 0; ks < 4; ++ks)
            a[ks] = *(const short8*)(ap + ks * 32);
        const short8* bw = (const short8*)wtf;
        #pragma unroll
        for (int ks = 0; ks < 4; ++ks) {
            #pragma unroll
            for (int t = 0; t < 8; ++t) {
                short8 bb = bw[(ks * 8 + t) * 64 + lane];
                acc[t] = __builtin_amdgcn_mfma_f32_16x16x32_bf16(a[ks], bb, acc[t], 0, 0, 0);
            }
        }
    }
    __syncthreads();

    for (int m = 1; m < 3; ++m) {
        short8 a[4];
        const short8* af = (const short8*)aggF;
        #pragma unroll
        for (int ks = 0; ks < 4; ++ks)
            a[ks] = af[(((m - 1) * 4 + ks) << 8) + wrow * 4 + quad];
        const short8* bw = ((const short8*)wtf) + m * 2048;   // 4*8*64 units per m
        #pragma unroll
        for (int ks = 0; ks < 4; ++ks) {
            #pragma unroll
            for (int t = 0; t < 8; ++t) {
                short8 bb = bw[(ks * 8 + t) * 64 + lane];
                acc[t] = __builtin_amdgcn_mfma_f32_16x16x32_bf16(a[ks], bb, acc[t], 0, 0, 0);
            }
        }
    }

    // epilogue: C/D map col=lane&15, row(local) = w*16 + quad*4 + reg
    // nontemporal: out is write-only, keep L2 for gather-hot xb/ent
    #pragma unroll
    for (int t = 0; t < 8; ++t) {
        int col = t * 16 + l15;
        float bj = b_lin[col] + 0.5f * (b_st[col] + b_ts[col]);
        #pragma unroll
        for (int i = 0; i < 4; ++i) {
            int row = row0 + w * 16 + quad * 4 + i;
            if (row < N)
                __builtin_nontemporal_store(acc[t][i] + bj, &out[(size_t)row * D + col]);
        }
    }
}

extern "C" void kernel_launch(void* const* d_in, const int* in_sizes, int n_in,
                              void* d_out, int out_size, void* d_ws, size_t ws_size,
                              hipStream_t stream)
{
    const float* x     = (const float*)d_in[0];
    const int*   ei    = (const int*)d_in[1];
    const float* W_lin = (const float*)d_in[2];
    const float* b_lin = (const float*)d_in[3];
    const float* W_st  = (const float*)d_in[4];
    const float* b_st  = (const float*)d_in[5];
    const float* W_ts  = (const float*)d_in[6];
    const float* b_ts  = (const float*)d_in[7];
    float*       out   = (float*)d_out;

    const int N = in_sizes[0] / D;
    const int E = in_sizes[1] / 2;
    const int M = 2 * N;

    char* base = (char*)d_ws;
    int* cnt             = (int*)base;            base += (size_t)M * 4;         // 0.8 MB
    int* ent             = (int*)base;            base += (size_t)M * BROW * 4;  // 25.6 MB
    unsigned short* xb   = (unsigned short*)base; base += (size_t)N * D * 2;     // 25.6 MB
    unsigned short* wtf  = (unsigned short*)base; base += 3 * 16384 * 2;         // 0.1 MB

    // only the compact count array needs zeroing (entries written before read)
    hipMemsetAsync(cnt, 0, (size_t)M * 4, stream);

    const int t8     = N * D / 8;
    const int nbuild = 8 * ((E + CH - 1) / CH);
    const int ncvt   = (t8 + 255) / 256;
    const int nprep  = 24;

    k_phase0<<<dim3(nbuild + ncvt + nprep), dim3(256), 0, stream>>>(
        x, ei, W_lin, W_st, W_ts, xb, wtf, cnt, ent, E, N, t8, nbuild, ncvt);
    k_fused<<<dim3((N + 63) / 64), dim3(256), 0, stream>>>(
        xb, cnt, ent, wtf, b_lin, b_st, b_ts, out, N);
}

// Round 3
// 247.638 us; speedup vs baseline: 1.2644x; 1.0878x over previous
//
#include <hip/hip_runtime.h>

#define D    128
#define BROW 32     // ints per bucket entry row = one 128-B line
#define CAPE 31     // entries per bucket; P(deg>=31) ~ 1e-13 per slot

typedef short short8 __attribute__((ext_vector_type(8)));
typedef float f32x4  __attribute__((ext_vector_type(4)));

static __device__ __forceinline__ unsigned short f2bf(float f) {
    union { float f; unsigned u; } v; v.f = f;
    unsigned r = v.u + 0x7FFFu + ((v.u >> 16) & 1u);   // RNE
    return (unsigned short)(r >> 16);
}
static __device__ __forceinline__ float bf2f(unsigned short h) {
    union { unsigned u; float f; } v; v.u = ((unsigned)h) << 16;
    return v.f;
}

// ---------------------------------------------------------------------------
// Phase-0 mega-kernel (grid-partitioned):
//  blocks [0, nbuild)        : XCD-partitioned bucket build (see r2 notes).
//  blocks [nbuild, +ncvt)    : x fp32 -> xb bf16, plus zeroed pad row xb[N]
//                              (gather-clamp target for uniform quad rounds).
//  blocks [nbuild+ncvt, +24) : weights -> bf16, scaled, MFMA-B-fragment order
// ---------------------------------------------------------------------------
#define CH 2048     // edges per chunk (8 per thread)

__global__ __launch_bounds__(256) void k_phase0(
    const float* __restrict__ x, const int* __restrict__ ei,
    const float* __restrict__ W_lin, const float* __restrict__ W_st,
    const float* __restrict__ W_ts,
    unsigned short* __restrict__ xb, unsigned short* __restrict__ wtf,
    int* __restrict__ cnt, int* __restrict__ ent,
    int E, int N, int t8, int nbuild, int ncvt)
{
    int b = blockIdx.x;
    if (b < nbuild) {
        const int part  = b & 7;
        const int chunk = b >> 3;
        const int P  = (2 * N + 7) >> 3;
        const int lo = part * P;
        const int hi = lo + P;
        int gg[16], vv[16], pp[16];
        #pragma unroll
        for (int k = 0; k < 8; ++k) {
            int e = chunk * CH + k * 256 + threadIdx.x;
            int s = -1, d = -1;
            if (e < E) { s = ei[e]; d = ei[E + e]; }
            int gts = N + s;
            gg[2 * k]     = (s >= 0 && d >= lo && d < hi) ? d : -1;
            vv[2 * k]     = s;
            gg[2 * k + 1] = (s >= 0 && gts >= lo && gts < hi) ? gts : -1;
            vv[2 * k + 1] = d;
        }
        // loop 1: issue all atomics (no result consumed between -> deep MLP)
        #pragma unroll
        for (int k = 0; k < 16; ++k)
            if (gg[k] >= 0) pp[k] = atomicAdd(cnt + gg[k], 1);
        // loop 2: dependent entry stores (L2-local under round-robin mapping)
        #pragma unroll
        for (int k = 0; k < 16; ++k)
            if (gg[k] >= 0 && pp[k] < CAPE)
                ent[(size_t)gg[k] * BROW + pp[k]] = vv[k];
    } else if (b < nbuild + ncvt) {
        int i = (b - nbuild) * 256 + threadIdx.x;   // 8 floats per thread
        if (i >= t8 + D / 8) return;
        if (i >= t8) {                              // zero pad row xb[N]
            *((uint4*)(xb + (size_t)i * 8)) = make_uint4(0, 0, 0, 0);
            return;
        }
        const float4* p = (const float4*)(x + (size_t)i * 8);
        float4 a = p[0], c = p[1];
        unsigned r0 = (unsigned)f2bf(a.x) | ((unsigned)f2bf(a.y) << 16);
        unsigned r1 = (unsigned)f2bf(a.z) | ((unsigned)f2bf(a.w) << 16);
        unsigned r2 = (unsigned)f2bf(c.x) | ((unsigned)f2bf(c.y) << 16);
        unsigned r3 = (unsigned)f2bf(c.z) | ((unsigned)f2bf(c.w) << 16);
        *((uint4*)(xb + (size_t)i * 8)) = make_uint4(r0, r1, r2, r3);
    } else {
        // wtf[((m*4+ks)*8+tile)*64+lane][j] =
        //   scale_m * W_m[ks*32+(lane>>4)*8+j][tile*16+(lane&15)]
        int g = (b - nbuild - ncvt) * 256 + threadIdx.x;
        if (g >= 3 * 4 * 8 * 64) return;
        int lane = g & 63;
        int tile = (g >> 6) & 7;
        int ks   = (g >> 9) & 3;
        int m    = g >> 11;
        const float* W = (m == 0) ? W_lin : (m == 1) ? W_st : W_ts;
        float scale = (m == 0) ? 1.0f : 0.5f;
        int n = tile * 16 + (lane & 15);
        int kbase = ks * 32 + (lane >> 4) * 8;
        unsigned short* dst = wtf + (size_t)g * 8;
        #pragma unroll
        for (int j = 0; j < 8; ++j)
            dst[j] = f2bf(W[(size_t)(kbase + j) * D + n] * scale);
    }
}

// ---------------------------------------------------------------------------
// Fused gather-mean + K=384 bf16 MFMA GEMM. Block = 256 thr = 4 waves,
// 32 output rows. LDS = 16 KB -> 6 blocks/CU (launch_bounds cap), ~24 waves.
// Phase A: 16 groups x 16 lanes; group owns 4 slots (slot=grp*4+s;
//   dir=slot>>5, i=slot&31). Lane l16 reads one short8 at k=l16*8 -> full
//   256-B row per group-load. Out-of-degree lanes clamp neighbor index to
//   the zeroed pad row xb[N] -> every slot is uniform ceil(deg/4) quad
//   rounds, no tail loop, no divergence; pad loads are L1-hot (same line).
//   2-deep software pipeline: quad r+1's 8 loads issue before quad r's
//   accumulation, hiding load latency under the VALU work. The bucket line
//   (ent row = exactly one 128-B line) + cnt prefetch one slot ahead.
//   Lane l16 owns A-frag unit (ks=l16>>2, qd=l16&3) -> one ds_write_b128.
// Phase B: out = [xb | agg_st | agg_ts] @ [Wl; .5Wst; .5Wts] + bias (MFMA).
//   4 waves: wave w -> row half (w&1)*16, N-tile base ((w>>1)*4)*16.
//   m=0 (dense xb) pass runs BEFORE __syncthreads (no LDS dependency).
// ---------------------------------------------------------------------------
__global__ __launch_bounds__(256, 6) void k_fused(
    const unsigned short* __restrict__ xb,
    const int* __restrict__ cnt, const int* __restrict__ ent,
    const unsigned short* __restrict__ wtf,
    const float* __restrict__ b_lin, const float* __restrict__ b_st,
    const float* __restrict__ b_ts,
    float* __restrict__ out, int N)
{
    __shared__ unsigned short aggF[2 * 4 * 32 * 4 * 8];   // 8192 ushorts = 16 KB

    const int tid  = threadIdx.x;
    const int row0 = blockIdx.x * 32;

    // ---- Phase A: gather means into A-fragment-ordered LDS ----
    {
        const int grp = tid >> 4;        // 16 groups of 16 lanes
        const int l16 = tid & 15;
        const unsigned short* xcol = xb + (l16 << 3);   // lane's 16-B column

        // prologue: prefetch slot 0's entry line + count
        int slot0 = grp * 4;
        int gn = row0 + (slot0 & 31); if (gn > N - 1) gn = N - 1;
        size_t g = (size_t)(slot0 >> 5) * N + gn;
        const int* row = ent + g * BROW;
        int4 h = *(const int4*)row;      // entries 0..3 (warms the single line)
        int dg = cnt[g];

        for (int s = 0; s < 4; ++s) {
            // issue next slot's prefetch before consuming current
            const int* rowN = row; int4 hn = h; int dgn = dg;
            if (s < 3) {
                int slot1 = grp * 4 + s + 1;
                int gn1 = row0 + (slot1 & 31); if (gn1 > N - 1) gn1 = N - 1;
                size_t g1 = (size_t)(slot1 >> 5) * N + gn1;
                rowN = ent + g1 * BROW;
                hn = *(const int4*)rowN;
                dgn = cnt[g1];
            }
            int slotc = grp * 4 + s;
            int dirc = slotc >> 5, ic = slotc & 31;
            int deg = dg > CAPE ? CAPE : dg;
            int R = (deg + 3) >> 2;      // uniform quad rounds (0 if deg==0)

            float a[8];
            #pragma unroll
            for (int t = 0; t < 8; ++t) a[t] = 0.f;

            if (R > 0) {
                // quad 0 from prefetched h, clamped to pad row N
                int n0 = h.x;
                int n1 = (1 < deg) ? h.y : N;
                int n2 = (2 < deg) ? h.z : N;
                int n3 = (3 < deg) ? h.w : N;
                short8 u0 = *(const short8*)(xcol + (size_t)n0 * D);
                short8 u1 = *(const short8*)(xcol + (size_t)n1 * D);
                short8 u2 = *(const short8*)(xcol + (size_t)n2 * D);
                short8 u3 = *(const short8*)(xcol + (size_t)n3 * D);
                for (int r = 1; r < R; ++r) {
                    int j = r * 4;       // j < deg guaranteed by R
                    int m0 = row[j];
                    int m1 = (j + 1 < deg) ? row[j + 1] : N;
                    int m2 = (j + 2 < deg) ? row[j + 2] : N;
                    int m3 = (j + 3 < deg) ? row[j + 3] : N;
                    // issue next quad's loads BEFORE accumulating current
                    short8 v0 = *(const short8*)(xcol + (size_t)m0 * D);
                    short8 v1 = *(const short8*)(xcol + (size_t)m1 * D);
                    short8 v2 = *(const short8*)(xcol + (size_t)m2 * D);
                    short8 v3 = *(const short8*)(xcol + (size_t)m3 * D);
                    #pragma unroll
                    for (int t = 0; t < 8; ++t)
                        a[t] += (bf2f((unsigned short)u0[t]) + bf2f((unsigned short)u1[t]))
                              + (bf2f((unsigned short)u2[t]) + bf2f((unsigned short)u3[t]));
                    u0 = v0; u1 = v1; u2 = v2; u3 = v3;
                }
                #pragma unroll
                for (int t = 0; t < 8; ++t)
                    a[t] += (bf2f((unsigned short)u0[t]) + bf2f((unsigned short)u1[t]))
                          + (bf2f((unsigned short)u2[t]) + bf2f((unsigned short)u3[t]));
            }

            float inv = 1.0f / fmaxf((float)deg, 1.0f);
            short8 o;
            #pragma unroll
            for (int t = 0; t < 8; ++t) o[t] = (short)f2bf(a[t] * inv);
            // unit U = ((dir*4+ks)*32 + i)*4 + qd ; lane l16 = ks*4+qd
            ((short8*)aggF)[((dirc * 4 + (l16 >> 2)) * 32 + ic) * 4 + (l16 & 3)] = o;

            row = rowN; h = hn; dg = dgn;
        }
    }

    // ---- Phase B: MFMA GEMM (32 rows x 128 cols, 4 waves) ----
    const int w     = tid >> 6;
    const int lane  = tid & 63;
    const int quad  = lane >> 4;
    const int l15   = lane & 15;
    const int rhalf = w & 1;            // 16-row half
    const int tb    = (w >> 1) * 4;     // N-tile base (4 tiles of 16 cols)
    const int wrow  = rhalf * 16 + l15; // local row 0..31
    int rowA = row0 + wrow; if (rowA > N - 1) rowA = N - 1;

    f32x4 acc[4];
    #pragma unroll
    for (int t = 0; t < 4; ++t) acc[t] = (f32x4){0.f, 0.f, 0.f, 0.f};

    // m = 0: dense xb pass, no LDS dependency -> before the barrier
    {
        short8 a[4];
        const unsigned short* ap = xb + (size_t)rowA * D + quad * 8;
        #pragma unroll
        for (int ks = 0; ks < 4; ++ks)
            a[ks] = *(const short8*)(ap + ks * 32);
        const short8* bw = (const short8*)wtf;
        #pragma unroll
        for (int ks = 0; ks < 4; ++ks) {
            #pragma unroll
            for (int t = 0; t < 4; ++t) {
                short8 bb = bw[(ks * 8 + tb + t) * 64 + lane];
                acc[t] = __builtin_amdgcn_mfma_f32_16x16x32_bf16(a[ks], bb, acc[t], 0, 0, 0);
            }
        }
    }
    __syncthreads();

    for (int m = 1; m < 3; ++m) {
        short8 a[4];
        const short8* af = (const short8*)aggF;
        #pragma unroll
        for (int ks = 0; ks < 4; ++ks)
            a[ks] = af[((m - 1) * 4 + ks) * 128 + wrow * 4 + quad];
        const short8* bw = ((const short8*)wtf) + m * 2048;   // 4*8*64 units per m
        #pragma unroll
        for (int ks = 0; ks < 4; ++ks) {
            #pragma unroll
            for (int t = 0; t < 4; ++t) {
                short8 bb = bw[(ks * 8 + tb + t) * 64 + lane];
                acc[t] = __builtin_amdgcn_mfma_f32_16x16x32_bf16(a[ks], bb, acc[t], 0, 0, 0);
            }
        }
    }

    // epilogue: C/D map col=lane&15, row(local) = rhalf*16 + quad*4 + reg
    // nontemporal: out is write-only, keep L2 for gather-hot xb/ent
    #pragma unroll
    for (int t = 0; t < 4; ++t) {
        int col = (tb + t) * 16 + l15;
        float bj = b_lin[col] + 0.5f * (b_st[col] + b_ts[col]);
        #pragma unroll
        for (int i = 0; i < 4; ++i) {
            int row = row0 + rhalf * 16 + quad * 4 + i;
            if (row < N)
                __builtin_nontemporal_store(acc[t][i] + bj, &out[(size_t)row * D + col]);
        }
    }
}

extern "C" void kernel_launch(void* const* d_in, const int* in_sizes, int n_in,
                              void* d_out, int out_size, void* d_ws, size_t ws_size,
                              hipStream_t stream)
{
    const float* x     = (const float*)d_in[0];
    const int*   ei    = (const int*)d_in[1];
    const float* W_lin = (const float*)d_in[2];
    const float* b_lin = (const float*)d_in[3];
    const float* W_st  = (const float*)d_in[4];
    const float* b_st  = (const float*)d_in[5];
    const float* W_ts  = (const float*)d_in[6];
    const float* b_ts  = (const float*)d_in[7];
    float*       out   = (float*)d_out;

    const int N = in_sizes[0] / D;
    const int E = in_sizes[1] / 2;
    const int M = 2 * N;

    char* base = (char*)d_ws;
    int* cnt             = (int*)base;            base += (size_t)M * 4;              // 0.8 MB
    int* ent             = (int*)base;            base += (size_t)M * BROW * 4;       // 25.6 MB
    unsigned short* xb   = (unsigned short*)base; base += (size_t)(N + 1) * D * 2;    // 25.6 MB (+pad row)
    unsigned short* wtf  = (unsigned short*)base; base += 3 * 16384 * 2;              // 0.1 MB

    // only the compact count array needs zeroing (entries written before read)
    hipMemsetAsync(cnt, 0, (size_t)M * 4, stream);

    const int t8     = N * D / 8;
    const int nbuild = 8 * ((E + CH - 1) / CH);
    const int ncvt   = (t8 + D / 8 + 255) / 256;
    const int nprep  = 24;

    k_phase0<<<dim3(nbuild + ncvt + nprep), dim3(256), 0, stream>>>(
        x, ei, W_lin, W_st, W_ts, xb, wtf, cnt, ent, E, N, t8, nbuild, ncvt);
    k_fused<<<dim3((N + 31) / 32), dim3(256), 0, stream>>>(
        xb, cnt, ent, wtf, b_lin, b_st, b_ts, out, N);
}

// Round 4
// 243.953 us; speedup vs baseline: 1.2835x; 1.0151x over previous
//
#include <hip/hip_runtime.h>

#define D    128
#define BROW 32     // ints per bucket entry row = one 128-B line
#define CAPE 31     // entries per bucket; P(deg>=31) ~ 1e-13 per slot

typedef short short8 __attribute__((ext_vector_type(8)));
typedef float f32x4  __attribute__((ext_vector_type(4)));

static __device__ __forceinline__ unsigned short f2bf(float f) {
    union { float f; unsigned u; } v; v.f = f;
    unsigned r = v.u + 0x7FFFu + ((v.u >> 16) & 1u);   // RNE
    return (unsigned short)(r >> 16);
}
static __device__ __forceinline__ float bf2f(unsigned short h) {
    union { unsigned u; float f; } v; v.u = ((unsigned)h) << 16;
    return v.f;
}

// ---------------------------------------------------------------------------
// Phase-0 mega-kernel (grid-partitioned):
//  blocks [0, nbuild)        : XCD-partitioned bucket build. 16 edges/thread;
//      all surviving atomics issued, then sched_barrier(0), then dependent
//      entry stores — the barrier stops the compiler re-fusing the loops
//      (r3 evidence: VGPR=12 => it had serialized the chains).
//  blocks [nbuild, +ncvt)    : x fp32 -> xb bf16, plus zeroed pad row xb[N]
//  blocks [nbuild+ncvt, +24) : weights -> bf16, scaled, MFMA-B-fragment order
// ---------------------------------------------------------------------------
#define CH 4096     // edges per chunk (16 per thread)

__global__ __launch_bounds__(256) void k_phase0(
    const float* __restrict__ x, const int* __restrict__ ei,
    const float* __restrict__ W_lin, const float* __restrict__ W_st,
    const float* __restrict__ W_ts,
    unsigned short* __restrict__ xb, unsigned short* __restrict__ wtf,
    int* __restrict__ cnt, int* __restrict__ ent,
    int E, int N, int t8, int nbuild, int ncvt)
{
    int b = blockIdx.x;
    if (b < nbuild) {
        const int part  = b & 7;
        const int chunk = b >> 3;
        const int P  = (2 * N + 7) >> 3;
        const int lo = part * P;
        const int hi = lo + P;
        int gg[32], vv[32], pp[32];
        #pragma unroll
        for (int k = 0; k < 16; ++k) {
            int e = chunk * CH + k * 256 + threadIdx.x;
            int s = -1, d = -1;
            if (e < E) { s = ei[e]; d = ei[E + e]; }
            int gts = N + s;
            gg[2 * k]     = (s >= 0 && d >= lo && d < hi) ? d : -1;
            vv[2 * k]     = s;
            gg[2 * k + 1] = (s >= 0 && gts >= lo && gts < hi) ? gts : -1;
            vv[2 * k + 1] = d;
        }
        // issue ALL surviving atomics first (deep MLP) ...
        #pragma unroll
        for (int k = 0; k < 32; ++k)
            if (gg[k] >= 0) pp[k] = atomicAdd(cnt + gg[k], 1);
        // ... and keep the split alive through codegen
        __builtin_amdgcn_sched_barrier(0);
        #pragma unroll
        for (int k = 0; k < 32; ++k)
            if (gg[k] >= 0 && pp[k] < CAPE)
                ent[(size_t)gg[k] * BROW + pp[k]] = vv[k];
    } else if (b < nbuild + ncvt) {
        int i = (b - nbuild) * 256 + threadIdx.x;   // 8 floats per thread
        if (i >= t8 + D / 8) return;
        if (i >= t8) {                              // zero pad row xb[N]
            *((uint4*)(xb + (size_t)i * 8)) = make_uint4(0, 0, 0, 0);
            return;
        }
        const float4* p = (const float4*)(x + (size_t)i * 8);
        float4 a = p[0], c = p[1];
        unsigned r0 = (unsigned)f2bf(a.x) | ((unsigned)f2bf(a.y) << 16);
        unsigned r1 = (unsigned)f2bf(a.z) | ((unsigned)f2bf(a.w) << 16);
        unsigned r2 = (unsigned)f2bf(c.x) | ((unsigned)f2bf(c.y) << 16);
        unsigned r3 = (unsigned)f2bf(c.z) | ((unsigned)f2bf(c.w) << 16);
        *((uint4*)(xb + (size_t)i * 8)) = make_uint4(r0, r1, r2, r3);
    } else {
        // wtf[((m*4+ks)*8+tile)*64+lane][j] =
        //   scale_m * W_m[ks*32+(lane>>4)*8+j][tile*16+(lane&15)]
        int g = (b - nbuild - ncvt) * 256 + threadIdx.x;
        if (g >= 3 * 4 * 8 * 64) return;
        int lane = g & 63;
        int tile = (g >> 6) & 7;
        int ks   = (g >> 9) & 3;
        int m    = g >> 11;
        const float* W = (m == 0) ? W_lin : (m == 1) ? W_st : W_ts;
        float scale = (m == 0) ? 1.0f : 0.5f;
        int n = tile * 16 + (lane & 15);
        int kbase = ks * 32 + (lane >> 4) * 8;
        unsigned short* dst = wtf + (size_t)g * 8;
        #pragma unroll
        for (int j = 0; j < 8; ++j)
            dst[j] = f2bf(W[(size_t)(kbase + j) * D + n] * scale);
    }
}

// ---------------------------------------------------------------------------
// Fused gather-mean + K=384 bf16 MFMA GEMM. Block = 256 thr = 4 waves,
// 32 output rows. LDS = 16 KB; __launch_bounds__(256,7) -> VGPR<=73,
// ~7 blocks/CU resident.
// Phase A: 16 groups x 16 lanes; group owns 4 slots. Lane l16 reads one
//   short8 at k=l16*8 -> full 256-B row per group-load. Out-of-degree lanes
//   clamp to zeroed pad row xb[N] (uniform quad rounds, no tail).
//   2-deep quad pipeline PINNED with sched_barrier(0): next quad's 4 loads
//   are guaranteed to issue before the current quad's accumulation (r3
//   evidence VGPR=40 showed the compiler had collapsed the unpinned version).
//   Next-slot ent-line + cnt prefetch pinned the same way.
// Phase B: out = [xb | agg_st | agg_ts] @ [Wl; .5Wst; .5Wts] + bias (MFMA).
//   4 waves: wave w -> row half (w&1)*16, N-tile base ((w>>1)*4)*16.
//   m=0 (dense xb) pass runs BEFORE __syncthreads (no LDS dependency).
// ---------------------------------------------------------------------------
__global__ __launch_bounds__(256, 7) void k_fused(
    const unsigned short* __restrict__ xb,
    const int* __restrict__ cnt, const int* __restrict__ ent,
    const unsigned short* __restrict__ wtf,
    const float* __restrict__ b_lin, const float* __restrict__ b_st,
    const float* __restrict__ b_ts,
    float* __restrict__ out, int N)
{
    __shared__ unsigned short aggF[2 * 4 * 32 * 4 * 8];   // 8192 ushorts = 16 KB

    const int tid  = threadIdx.x;
    const int row0 = blockIdx.x * 32;

    // ---- Phase A: gather means into A-fragment-ordered LDS ----
    {
        const int grp = tid >> 4;        // 16 groups of 16 lanes
        const int l16 = tid & 15;
        const unsigned short* xcol = xb + (l16 << 3);   // lane's 16-B column

        // prologue: prefetch slot 0's entry line + count
        int slot0 = grp * 4;
        int gn = row0 + (slot0 & 31); if (gn > N - 1) gn = N - 1;
        size_t g = (size_t)(slot0 >> 5) * N + gn;
        const int* row = ent + g * BROW;
        int4 h = *(const int4*)row;      // entries 0..3 (warms the single line)
        int dg = cnt[g];

        for (int s = 0; s < 4; ++s) {
            // issue next slot's prefetch before consuming current
            const int* rowN = row; int4 hn = h; int dgn = dg;
            if (s < 3) {
                int slot1 = grp * 4 + s + 1;
                int gn1 = row0 + (slot1 & 31); if (gn1 > N - 1) gn1 = N - 1;
                size_t g1 = (size_t)(slot1 >> 5) * N + gn1;
                rowN = ent + g1 * BROW;
                hn = *(const int4*)rowN;
                dgn = cnt[g1];
            }
            __builtin_amdgcn_sched_barrier(0);   // pin prefetch issue early
            int slotc = grp * 4 + s;
            int dirc = slotc >> 5, ic = slotc & 31;
            int deg = dg > CAPE ? CAPE : dg;
            int R = (deg + 3) >> 2;      // uniform quad rounds (0 if deg==0)

            float a[8];
            #pragma unroll
            for (int t = 0; t < 8; ++t) a[t] = 0.f;

            if (R > 0) {
                // quad 0 from prefetched h, clamped to pad row N
                int n0 = h.x;
                int n1 = (1 < deg) ? h.y : N;
                int n2 = (2 < deg) ? h.z : N;
                int n3 = (3 < deg) ? h.w : N;
                short8 u0 = *(const short8*)(xcol + (size_t)n0 * D);
                short8 u1 = *(const short8*)(xcol + (size_t)n1 * D);
                short8 u2 = *(const short8*)(xcol + (size_t)n2 * D);
                short8 u3 = *(const short8*)(xcol + (size_t)n3 * D);
                for (int r = 1; r < R; ++r) {
                    int j = r * 4;       // j < deg guaranteed by R
                    int m0 = row[j];
                    int m1 = (j + 1 < deg) ? row[j + 1] : N;
                    int m2 = (j + 2 < deg) ? row[j + 2] : N;
                    int m3 = (j + 3 < deg) ? row[j + 3] : N;
                    // issue next quad's loads ...
                    short8 v0 = *(const short8*)(xcol + (size_t)m0 * D);
                    short8 v1 = *(const short8*)(xcol + (size_t)m1 * D);
                    short8 v2 = *(const short8*)(xcol + (size_t)m2 * D);
                    short8 v3 = *(const short8*)(xcol + (size_t)m3 * D);
                    // ... and forbid the scheduler from sinking them below
                    __builtin_amdgcn_sched_barrier(0);
                    #pragma unroll
                    for (int t = 0; t < 8; ++t)
                        a[t] += (bf2f((unsigned short)u0[t]) + bf2f((unsigned short)u1[t]))
                              + (bf2f((unsigned short)u2[t]) + bf2f((unsigned short)u3[t]));
                    u0 = v0; u1 = v1; u2 = v2; u3 = v3;
                }
                #pragma unroll
                for (int t = 0; t < 8; ++t)
                    a[t] += (bf2f((unsigned short)u0[t]) + bf2f((unsigned short)u1[t]))
                          + (bf2f((unsigned short)u2[t]) + bf2f((unsigned short)u3[t]));
            }

            float inv = 1.0f / fmaxf((float)deg, 1.0f);
            short8 o;
            #pragma unroll
            for (int t = 0; t < 8; ++t) o[t] = (short)f2bf(a[t] * inv);
            // unit U = ((dir*4+ks)*32 + i)*4 + qd ; lane l16 = ks*4+qd
            ((short8*)aggF)[((dirc * 4 + (l16 >> 2)) * 32 + ic) * 4 + (l16 & 3)] = o;

            row = rowN; h = hn; dg = dgn;
        }
    }

    // ---- Phase B: MFMA GEMM (32 rows x 128 cols, 4 waves) ----
    const int w     = tid >> 6;
    const int lane  = tid & 63;
    const int quad  = lane >> 4;
    const int l15   = lane & 15;
    const int rhalf = w & 1;            // 16-row half
    const int tb    = (w >> 1) * 4;     // N-tile base (4 tiles of 16 cols)
    const int wrow  = rhalf * 16 + l15; // local row 0..31
    int rowA = row0 + wrow; if (rowA > N - 1) rowA = N - 1;

    f32x4 acc[4];
    #pragma unroll
    for (int t = 0; t < 4; ++t) acc[t] = (f32x4){0.f, 0.f, 0.f, 0.f};

    // m = 0: dense xb pass, no LDS dependency -> before the barrier
    {
        short8 a[4];
        const unsigned short* ap = xb + (size_t)rowA * D + quad * 8;
        #pragma unroll
        for (int ks = 0; ks < 4; ++ks)
            a[ks] = *(const short8*)(ap + ks * 32);
        const short8* bw = (const short8*)wtf;
        #pragma unroll
        for (int ks = 0; ks < 4; ++ks) {
            #pragma unroll
            for (int t = 0; t < 4; ++t) {
                short8 bb = bw[(ks * 8 + tb + t) * 64 + lane];
                acc[t] = __builtin_amdgcn_mfma_f32_16x16x32_bf16(a[ks], bb, acc[t], 0, 0, 0);
            }
        }
    }
    __syncthreads();

    for (int m = 1; m < 3; ++m) {
        short8 a[4];
        const short8* af = (const short8*)aggF;
        #pragma unroll
        for (int ks = 0; ks < 4; ++ks)
            a[ks] = af[((m - 1) * 4 + ks) * 128 + wrow * 4 + quad];
        const short8* bw = ((const short8*)wtf) + m * 2048;   // 4*8*64 units per m
        #pragma unroll
        for (int ks = 0; ks < 4; ++ks) {
            #pragma unroll
            for (int t = 0; t < 4; ++t) {
                short8 bb = bw[(ks * 8 + tb + t) * 64 + lane];
                acc[t] = __builtin_amdgcn_mfma_f32_16x16x32_bf16(a[ks], bb, acc[t], 0, 0, 0);
            }
        }
    }

    // epilogue: C/D map col=lane&15, row(local) = rhalf*16 + quad*4 + reg
    // nontemporal: out is write-only, keep L2 for gather-hot xb/ent
    #pragma unroll
    for (int t = 0; t < 4; ++t) {
        int col = (tb + t) * 16 + l15;
        float bj = b_lin[col] + 0.5f * (b_st[col] + b_ts[col]);
        #pragma unroll
        for (int i = 0; i < 4; ++i) {
            int row = row0 + rhalf * 16 + quad * 4 + i;
            if (row < N)
                __builtin_nontemporal_store(acc[t][i] + bj, &out[(size_t)row * D + col]);
        }
    }
}

extern "C" void kernel_launch(void* const* d_in, const int* in_sizes, int n_in,
                              void* d_out, int out_size, void* d_ws, size_t ws_size,
                              hipStream_t stream)
{
    const float* x     = (const float*)d_in[0];
    const int*   ei    = (const int*)d_in[1];
    const float* W_lin = (const float*)d_in[2];
    const float* b_lin = (const float*)d_in[3];
    const float* W_st  = (const float*)d_in[4];
    const float* b_st  = (const float*)d_in[5];
    const float* W_ts  = (const float*)d_in[6];
    const float* b_ts  = (const float*)d_in[7];
    float*       out   = (float*)d_out;

    const int N = in_sizes[0] / D;
    const int E = in_sizes[1] / 2;
    const int M = 2 * N;

    char* base = (char*)d_ws;
    int* cnt             = (int*)base;            base += (size_t)M * 4;              // 0.8 MB
    int* ent             = (int*)base;            base += (size_t)M * BROW * 4;       // 25.6 MB
    unsigned short* xb   = (unsigned short*)base; base += (size_t)(N + 1) * D * 2;    // 25.6 MB (+pad row)
    unsigned short* wtf  = (unsigned short*)base; base += 3 * 16384 * 2;              // 0.1 MB

    // only the compact count array needs zeroing (entries written before read)
    hipMemsetAsync(cnt, 0, (size_t)M * 4, stream);

    const int t8     = N * D / 8;
    const int nbuild = 8 * ((E + CH - 1) / CH);
    const int ncvt   = (t8 + D / 8 + 255) / 256;
    const int nprep  = 24;

    k_phase0<<<dim3(nbuild + ncvt + nprep), dim3(256), 0, stream>>>(
        x, ei, W_lin, W_st, W_ts, xb, wtf, cnt, ent, E, N, t8, nbuild, ncvt);
    k_fused<<<dim3((N + 31) / 32), dim3(256), 0, stream>>>(
        xb, cnt, ent, wtf, b_lin, b_st, b_ts, out, N);
}